// Round 1
// baseline (819.506 us; speedup 1.0000x reference)
//
#include <hip/hip_runtime.h>
#include <hip/hip_bf16.h>
#include <math.h>

#define N_PROP 1024
#define DAPP   2048
#define DK     128

// ---------------------------------------------------------------------------
// Kernel 0: seed Q/K/V with their biases (ws is poisoned 0xAA before each call)
// ---------------------------------------------------------------------------
__global__ __launch_bounds__(256) void init_bias_kernel(
    const float* __restrict__ bQ, const float* __restrict__ bK,
    const float* __restrict__ bV,
    float* __restrict__ Q, float* __restrict__ K, float* __restrict__ V) {
  int i = blockIdx.x * 256 + threadIdx.x;
  if (i < N_PROP * DK) {
    int c = i & (DK - 1);
    Q[i] = bQ[c];
    K[i] = bK[c];
    V[i] = bV[c];
  }
}

// ---------------------------------------------------------------------------
// Kernel 1: fused QKV projection.  C = X (1024x2048) @ W^T (2048x128) per proj.
// 64x64 output tile, 4x4 register blocking, split-k=4 via atomicAdd.
// grid = (6 col-tiles [3 proj x 2], 16 row-tiles, 4 k-splits), block = 256.
// ---------------------------------------------------------------------------
#define BM 64
#define BN 64
#define KC 32
#define KSPLIT_CHUNK 512

__global__ __launch_bounds__(256) void proj_kernel(
    const float* __restrict__ X,
    const float* __restrict__ WQ, const float* __restrict__ WK,
    const float* __restrict__ WV,
    float* __restrict__ Q, float* __restrict__ K, float* __restrict__ V) {
  __shared__ __attribute__((aligned(16))) float As[KC][BM + 4];
  __shared__ __attribute__((aligned(16))) float Bs[KC][BN + 4];

  const int nt = blockIdx.x;        // 0..5 : which 64-col slab of the 384 cols
  const int mt = blockIdx.y;        // 0..15
  const int kz = blockIdx.z;        // 0..3
  const int row0 = mt * BM;
  const int proj = nt >> 1;         // 0=Q 1=K 2=V
  const int col0 = (nt & 1) * 64;   // col offset inside the 128-wide proj

  const float* __restrict__ W = (proj == 0) ? WQ : ((proj == 1) ? WK : WV);
  float* __restrict__ O = (proj == 0) ? Q : ((proj == 1) ? K : V);

  const int t  = threadIdx.x;
  const int tx = t & 15, ty = t >> 4;   // 16x16 thread grid, 4x4 each
  const int kk = t & 31, mm = t >> 5;   // loader coords

  float acc[4][4] = {};

  const int k0base = kz * KSPLIT_CHUNK;
  for (int k0 = k0base; k0 < k0base + KSPLIT_CHUNK; k0 += KC) {
    __syncthreads();
#pragma unroll
    for (int r = 0; r < 8; ++r) {
      As[kk][mm + r * 8] = X[(size_t)(row0 + mm + r * 8) * DAPP + k0 + kk];
      Bs[kk][mm + r * 8] = W[(size_t)(col0 + mm + r * 8) * DAPP + k0 + kk];
    }
    __syncthreads();
#pragma unroll
    for (int k = 0; k < KC; ++k) {
      float4 a = *(const float4*)&As[k][ty * 4];
      float4 b = *(const float4*)&Bs[k][tx * 4];
      acc[0][0] += a.x * b.x; acc[0][1] += a.x * b.y; acc[0][2] += a.x * b.z; acc[0][3] += a.x * b.w;
      acc[1][0] += a.y * b.x; acc[1][1] += a.y * b.y; acc[1][2] += a.y * b.z; acc[1][3] += a.y * b.w;
      acc[2][0] += a.z * b.x; acc[2][1] += a.z * b.y; acc[2][2] += a.z * b.z; acc[2][3] += a.z * b.w;
      acc[3][0] += a.w * b.x; acc[3][1] += a.w * b.y; acc[3][2] += a.w * b.z; acc[3][3] += a.w * b.w;
    }
  }

#pragma unroll
  for (int i = 0; i < 4; ++i)
#pragma unroll
    for (int j = 0; j < 4; ++j)
      atomicAdd(&O[(size_t)(row0 + ty * 4 + i) * DK + col0 + tx * 4 + j],
                acc[i][j]);
}

// ---------------------------------------------------------------------------
// Kernel 2: S = (Q @ K^T) / sqrt(128).  1024x1024 output, k=128.
// grid = (16, 16), block = 256, same tile structure, no split-k.
// ---------------------------------------------------------------------------
__global__ __launch_bounds__(256) void score_kernel(
    const float* __restrict__ Q, const float* __restrict__ Kmat,
    float* __restrict__ S) {
  __shared__ __attribute__((aligned(16))) float As[KC][BM + 4];
  __shared__ __attribute__((aligned(16))) float Bs[KC][BN + 4];

  const int col0 = blockIdx.x * BN;
  const int row0 = blockIdx.y * BM;
  const int t  = threadIdx.x;
  const int tx = t & 15, ty = t >> 4;
  const int kk = t & 31, mm = t >> 5;

  float acc[4][4] = {};

  for (int k0 = 0; k0 < DK; k0 += KC) {
    __syncthreads();
#pragma unroll
    for (int r = 0; r < 8; ++r) {
      As[kk][mm + r * 8] = Q[(size_t)(row0 + mm + r * 8) * DK + k0 + kk];
      Bs[kk][mm + r * 8] = Kmat[(size_t)(col0 + mm + r * 8) * DK + k0 + kk];
    }
    __syncthreads();
#pragma unroll
    for (int k = 0; k < KC; ++k) {
      float4 a = *(const float4*)&As[k][ty * 4];
      float4 b = *(const float4*)&Bs[k][tx * 4];
      acc[0][0] += a.x * b.x; acc[0][1] += a.x * b.y; acc[0][2] += a.x * b.z; acc[0][3] += a.x * b.w;
      acc[1][0] += a.y * b.x; acc[1][1] += a.y * b.y; acc[1][2] += a.y * b.z; acc[1][3] += a.y * b.w;
      acc[2][0] += a.z * b.x; acc[2][1] += a.z * b.y; acc[2][2] += a.z * b.z; acc[2][3] += a.z * b.w;
      acc[3][0] += a.w * b.x; acc[3][1] += a.w * b.y; acc[3][2] += a.w * b.z; acc[3][3] += a.w * b.w;
    }
  }

  const float scale = 0.08838834764831845f; // 1/sqrt(128)
#pragma unroll
  for (int i = 0; i < 4; ++i)
#pragma unroll
    for (int j = 0; j < 4; ++j)
      S[(size_t)(row0 + ty * 4 + i) * N_PROP + col0 + tx * 4 + j] =
          acc[i][j] * scale;
}

// ---------------------------------------------------------------------------
// Kernel 3: per-row fused geometric bias + softmax + P@V.
// One block (256 thr) per row m.  Streams pos[m,:,:] (512 KB) from HBM —
// this is the 512 MiB roofline term.  V (512 KB) stays L2-resident.
// ---------------------------------------------------------------------------
__global__ __launch_bounds__(256) void fused_row_kernel(
    const float* __restrict__ pos, const float* __restrict__ S,
    const float* __restrict__ V, const float* __restrict__ wg,
    const float* __restrict__ bg, float* __restrict__ out) {
  __shared__ __attribute__((aligned(16))) float logits[N_PROP];
  __shared__ __attribute__((aligned(16))) float wgs[DK];
  __shared__ __attribute__((aligned(16))) float red[256];
  __shared__ float wred[4];

  const int m = blockIdx.x;
  const int t = threadIdx.x;

  if (t < DK) wgs[t] = wg[t];
  __syncthreads();

  const int hw = t >> 5;       // half-wave id 0..7
  const int l  = t & 31;       // lane within half-wave
  const float4 w4 = *(const float4*)&wgs[l * 4];
  const float bG = bg[0];
  const float* __restrict__ posrow = pos + (size_t)m * N_PROP * DK;
  const float* __restrict__ Srow   = S + (size_t)m * N_PROP;

  // ---- phase 1: logits[n] = S[m,n] + relu(pos[m,n,:].wg + bG) ----
  for (int it = 0; it < 128; ++it) {
    const int n = it * 8 + hw;
    const float4 p4 = *(const float4*)(posrow + (size_t)n * DK + l * 4);
    float d = p4.x * w4.x + p4.y * w4.y + p4.z * w4.z + p4.w * w4.w;
#pragma unroll
    for (int off = 16; off; off >>= 1) d += __shfl_xor(d, off, 64);
    if (l == 0) {
      float g = d + bG;
      g = g > 0.0f ? g : 0.0f;
      logits[n] = Srow[n] + g;
    }
  }
  __syncthreads();

  // ---- phase 2: row softmax over logits[0..1023] ----
  float mx = -INFINITY;
  for (int n = t; n < N_PROP; n += 256) mx = fmaxf(mx, logits[n]);
#pragma unroll
  for (int off = 32; off; off >>= 1) mx = fmaxf(mx, __shfl_xor(mx, off, 64));
  if ((t & 63) == 0) wred[t >> 6] = mx;
  __syncthreads();
  mx = fmaxf(fmaxf(wred[0], wred[1]), fmaxf(wred[2], wred[3]));
  __syncthreads();

  float sum = 0.0f;
  for (int n = t; n < N_PROP; n += 256) {
    float e = __expf(logits[n] - mx);
    logits[n] = e;
    sum += e;
  }
#pragma unroll
  for (int off = 32; off; off >>= 1) sum += __shfl_xor(sum, off, 64);
  if ((t & 63) == 0) wred[t >> 6] = sum;
  __syncthreads();   // also orders logits[] writes before phase 3 reads
  sum = wred[0] + wred[1] + wred[2] + wred[3];
  const float inv = 1.0f / sum;

  // ---- phase 3: out[m,d] = inv * sum_n p[n] * V[n,d] ----
  const int d    = t & 127;
  const int half = t >> 7;
  float acc = 0.0f;
#pragma unroll 8
  for (int n = half; n < N_PROP; n += 2)
    acc += logits[n] * V[(size_t)n * DK + d];
  red[t] = acc;
  __syncthreads();
  if (t < DK) out[(size_t)m * DK + t] = (red[t] + red[t + DK]) * inv;
}

// ---------------------------------------------------------------------------
extern "C" void kernel_launch(void* const* d_in, const int* in_sizes, int n_in,
                              void* d_out, int out_size, void* d_ws,
                              size_t ws_size, hipStream_t stream) {
  const float* app = (const float*)d_in[0];   // (1024, 2048)
  const float* pos = (const float*)d_in[1];   // (1024, 1024, 128)
  const float* WQw = (const float*)d_in[2];
  const float* WQb = (const float*)d_in[3];
  const float* WKw = (const float*)d_in[4];
  const float* WKb = (const float*)d_in[5];
  const float* WVw = (const float*)d_in[6];
  const float* WVb = (const float*)d_in[7];
  const float* WGw = (const float*)d_in[8];
  const float* WGb = (const float*)d_in[9];
  float* out = (float*)d_out;

  float* ws = (float*)d_ws;
  float* Q = ws;                         // 1024*128
  float* K = ws + 131072;                // 1024*128
  float* V = ws + 262144;                // 1024*128
  float* S = ws + 393216;                // 1024*1024

  init_bias_kernel<<<dim3(512), dim3(256), 0, stream>>>(WQb, WKb, WVb, Q, K, V);

  proj_kernel<<<dim3(6, 16, 4), dim3(256), 0, stream>>>(app, WQw, WKw, WVw,
                                                        Q, K, V);

  score_kernel<<<dim3(16, 16), dim3(256), 0, stream>>>(Q, K, S);

  fused_row_kernel<<<dim3(1024), dim3(256), 0, stream>>>(pos, S, V, WGw, WGb,
                                                         out);
}

// Round 2
// 814.448 us; speedup vs baseline: 1.0062x; 1.0062x over previous
//
#include <hip/hip_runtime.h>
#include <hip/hip_bf16.h>
#include <math.h>

#define N_PROP 1024
#define DAPP   2048
#define DK     128

// ---------------------------------------------------------------------------
// Kernel 0: seed Q/K/V with their biases (ws is poisoned 0xAA before each call)
// ---------------------------------------------------------------------------
__global__ __launch_bounds__(256) void init_bias_kernel(
    const float* __restrict__ bQ, const float* __restrict__ bK,
    const float* __restrict__ bV,
    float* __restrict__ Q, float* __restrict__ K, float* __restrict__ V) {
  int i = blockIdx.x * 256 + threadIdx.x;
  if (i < N_PROP * DK) {
    int c = i & (DK - 1);
    Q[i] = bQ[c];
    K[i] = bK[c];
    V[i] = bV[c];
  }
}

// ---------------------------------------------------------------------------
// Kernel 1: fused QKV projection.  C = X (1024x2048) @ W^T (2048x128) per proj.
// 64x64 output tile, 4x4 register blocking, split-k=4 via atomicAdd.
// grid = (6 col-tiles [3 proj x 2], 16 row-tiles, 4 k-splits), block = 256.
// ---------------------------------------------------------------------------
#define BM 64
#define BN 64
#define KC 32
#define KSPLIT_CHUNK 512

__global__ __launch_bounds__(256) void proj_kernel(
    const float* __restrict__ X,
    const float* __restrict__ WQ, const float* __restrict__ WK,
    const float* __restrict__ WV,
    float* __restrict__ Q, float* __restrict__ K, float* __restrict__ V) {
  __shared__ __attribute__((aligned(16))) float As[KC][BM + 4];
  __shared__ __attribute__((aligned(16))) float Bs[KC][BN + 4];

  const int nt = blockIdx.x;        // 0..5 : which 64-col slab of the 384 cols
  const int mt = blockIdx.y;        // 0..15
  const int kz = blockIdx.z;        // 0..3
  const int row0 = mt * BM;
  const int proj = nt >> 1;         // 0=Q 1=K 2=V
  const int col0 = (nt & 1) * 64;   // col offset inside the 128-wide proj

  const float* __restrict__ W = (proj == 0) ? WQ : ((proj == 1) ? WK : WV);
  float* __restrict__ O = (proj == 0) ? Q : ((proj == 1) ? K : V);

  const int t  = threadIdx.x;
  const int tx = t & 15, ty = t >> 4;   // 16x16 thread grid, 4x4 each
  const int kk = t & 31, mm = t >> 5;   // loader coords

  float acc[4][4] = {};

  const int k0base = kz * KSPLIT_CHUNK;
  for (int k0 = k0base; k0 < k0base + KSPLIT_CHUNK; k0 += KC) {
    __syncthreads();
#pragma unroll
    for (int r = 0; r < 8; ++r) {
      As[kk][mm + r * 8] = X[(size_t)(row0 + mm + r * 8) * DAPP + k0 + kk];
      Bs[kk][mm + r * 8] = W[(size_t)(col0 + mm + r * 8) * DAPP + k0 + kk];
    }
    __syncthreads();
#pragma unroll
    for (int k = 0; k < KC; ++k) {
      float4 a = *(const float4*)&As[k][ty * 4];
      float4 b = *(const float4*)&Bs[k][tx * 4];
      acc[0][0] += a.x * b.x; acc[0][1] += a.x * b.y; acc[0][2] += a.x * b.z; acc[0][3] += a.x * b.w;
      acc[1][0] += a.y * b.x; acc[1][1] += a.y * b.y; acc[1][2] += a.y * b.z; acc[1][3] += a.y * b.w;
      acc[2][0] += a.z * b.x; acc[2][1] += a.z * b.y; acc[2][2] += a.z * b.z; acc[2][3] += a.z * b.w;
      acc[3][0] += a.w * b.x; acc[3][1] += a.w * b.y; acc[3][2] += a.w * b.z; acc[3][3] += a.w * b.w;
    }
  }

#pragma unroll
  for (int i = 0; i < 4; ++i)
#pragma unroll
    for (int j = 0; j < 4; ++j)
      atomicAdd(&O[(size_t)(row0 + ty * 4 + i) * DK + col0 + tx * 4 + j],
                acc[i][j]);
}

// ---------------------------------------------------------------------------
// Kernel 2: S = (Q @ K^T) / sqrt(128).  1024x1024 output, k=128.
// grid = (16, 16), block = 256.
// ---------------------------------------------------------------------------
__global__ __launch_bounds__(256) void score_kernel(
    const float* __restrict__ Q, const float* __restrict__ Kmat,
    float* __restrict__ S) {
  __shared__ __attribute__((aligned(16))) float As[KC][BM + 4];
  __shared__ __attribute__((aligned(16))) float Bs[KC][BN + 4];

  const int col0 = blockIdx.x * BN;
  const int row0 = blockIdx.y * BM;
  const int t  = threadIdx.x;
  const int tx = t & 15, ty = t >> 4;
  const int kk = t & 31, mm = t >> 5;

  float acc[4][4] = {};

  for (int k0 = 0; k0 < DK; k0 += KC) {
    __syncthreads();
#pragma unroll
    for (int r = 0; r < 8; ++r) {
      As[kk][mm + r * 8] = Q[(size_t)(row0 + mm + r * 8) * DK + k0 + kk];
      Bs[kk][mm + r * 8] = Kmat[(size_t)(col0 + mm + r * 8) * DK + k0 + kk];
    }
    __syncthreads();
#pragma unroll
    for (int k = 0; k < KC; ++k) {
      float4 a = *(const float4*)&As[k][ty * 4];
      float4 b = *(const float4*)&Bs[k][tx * 4];
      acc[0][0] += a.x * b.x; acc[0][1] += a.x * b.y; acc[0][2] += a.x * b.z; acc[0][3] += a.x * b.w;
      acc[1][0] += a.y * b.x; acc[1][1] += a.y * b.y; acc[1][2] += a.y * b.z; acc[1][3] += a.y * b.w;
      acc[2][0] += a.z * b.x; acc[2][1] += a.z * b.y; acc[2][2] += a.z * b.z; acc[2][3] += a.z * b.w;
      acc[3][0] += a.w * b.x; acc[3][1] += a.w * b.y; acc[3][2] += a.w * b.z; acc[3][3] += a.w * b.w;
    }
  }

  const float scale = 0.08838834764831845f; // 1/sqrt(128)
#pragma unroll
  for (int i = 0; i < 4; ++i)
#pragma unroll
    for (int j = 0; j < 4; ++j)
      S[(size_t)(row0 + ty * 4 + i) * N_PROP + col0 + tx * 4 + j] =
          acc[i][j] * scale;
}

// ---------------------------------------------------------------------------
// Kernel 3: geometric bias, pure stream of the 512 MiB pos tensor.
// S[m*N+n] += relu(pos[m,n,:].wg + bg).  One 128-dim dot per 32-lane half.
// grid = 2048 blocks x 256 thr = 8 blocks/CU, full 32-wave occupancy.
// 1M rows / (2048*8 rows per sweep) = 64 grid-stride iterations.
// ---------------------------------------------------------------------------
__global__ __launch_bounds__(256) void bias_kernel(
    const float* __restrict__ pos, float* __restrict__ S,
    const float* __restrict__ wg, const float* __restrict__ bg) {
  const int t  = threadIdx.x;
  const int l  = t & 31;     // lane in half-wave
  const int hw = t >> 5;     // half-wave id 0..7

  const float4 w4 = *(const float4*)&wg[l * 4];   // 32 lanes cover 128 dims
  const float bG = bg[0];

  const size_t total  = (size_t)N_PROP * N_PROP;
  const size_t stride = (size_t)gridDim.x * 8;
  for (size_t row = (size_t)blockIdx.x * 8 + hw; row < total; row += stride) {
    const float4 p4 = *(const float4*)(pos + row * DK + (l << 2));
    float d = p4.x * w4.x + p4.y * w4.y + p4.z * w4.z + p4.w * w4.w;
#pragma unroll
    for (int off = 16; off; off >>= 1) d += __shfl_xor(d, off, 64);
    if (l == 0) {
      float g = d + bG;
      S[row] += g > 0.0f ? g : 0.0f;
    }
  }
}

// ---------------------------------------------------------------------------
// Kernel 4: per-row softmax + P@V.  One block per row m.
// S row read as float4; PV with float4 V loads (V is L2-resident, 512 KB).
// ---------------------------------------------------------------------------
__global__ __launch_bounds__(256) void softmax_pv_kernel(
    const float* __restrict__ S, const float* __restrict__ V,
    float* __restrict__ out) {
  __shared__ __attribute__((aligned(16))) float p[N_PROP];
  __shared__ __attribute__((aligned(16))) float4 accs[256];
  __shared__ float wred[4];

  const int m = blockIdx.x;
  const int t = threadIdx.x;
  const float* __restrict__ Srow = S + (size_t)m * N_PROP;

  // ---- softmax ----
  const float4 s4 = ((const float4*)Srow)[t];
  float mx = fmaxf(fmaxf(s4.x, s4.y), fmaxf(s4.z, s4.w));
#pragma unroll
  for (int off = 32; off; off >>= 1) mx = fmaxf(mx, __shfl_xor(mx, off, 64));
  if ((t & 63) == 0) wred[t >> 6] = mx;
  __syncthreads();
  mx = fmaxf(fmaxf(wred[0], wred[1]), fmaxf(wred[2], wred[3]));

  const float e0 = __expf(s4.x - mx), e1 = __expf(s4.y - mx);
  const float e2 = __expf(s4.z - mx), e3 = __expf(s4.w - mx);
  ((float4*)p)[t] = make_float4(e0, e1, e2, e3);
  float sum = e0 + e1 + e2 + e3;
#pragma unroll
  for (int off = 32; off; off >>= 1) sum += __shfl_xor(sum, off, 64);
  __syncthreads();               // wred read-before-write hazard barrier
  if ((t & 63) == 0) wred[t >> 6] = sum;
  __syncthreads();               // also publishes p[]
  sum = wred[0] + wred[1] + wred[2] + wred[3];
  const float inv = 1.0f / sum;

  // ---- P @ V : 8 n-groups x 32 lanes x float4 cols ----
  const int dq = (t & 31) << 2;  // col offset 0..124 (x4)
  const int ng = t >> 5;         // 0..7
  float4 acc = make_float4(0.f, 0.f, 0.f, 0.f);
  for (int n = ng; n < N_PROP; n += 8) {
    const float pw = p[n];
    const float4 v4 = *(const float4*)&V[(size_t)n * DK + dq];
    acc.x += pw * v4.x; acc.y += pw * v4.y;
    acc.z += pw * v4.z; acc.w += pw * v4.w;
  }
  accs[t] = acc;
  __syncthreads();
  if (t < 32) {
    float4 r = accs[t];
#pragma unroll
    for (int g = 1; g < 8; ++g) {
      const float4 o = accs[t + g * 32];
      r.x += o.x; r.y += o.y; r.z += o.z; r.w += o.w;
    }
    r.x *= inv; r.y *= inv; r.z *= inv; r.w *= inv;
    *(float4*)&out[(size_t)m * DK + (t << 2)] = r;
  }
}

// ---------------------------------------------------------------------------
extern "C" void kernel_launch(void* const* d_in, const int* in_sizes, int n_in,
                              void* d_out, int out_size, void* d_ws,
                              size_t ws_size, hipStream_t stream) {
  const float* app = (const float*)d_in[0];   // (1024, 2048)
  const float* pos = (const float*)d_in[1];   // (1024, 1024, 128)
  const float* WQw = (const float*)d_in[2];
  const float* WQb = (const float*)d_in[3];
  const float* WKw = (const float*)d_in[4];
  const float* WKb = (const float*)d_in[5];
  const float* WVw = (const float*)d_in[6];
  const float* WVb = (const float*)d_in[7];
  const float* WGw = (const float*)d_in[8];
  const float* WGb = (const float*)d_in[9];
  float* out = (float*)d_out;

  float* ws = (float*)d_ws;
  float* Q = ws;                         // 1024*128
  float* K = ws + 131072;                // 1024*128
  float* V = ws + 262144;                // 1024*128
  float* S = ws + 393216;                // 1024*1024

  init_bias_kernel<<<dim3(512), dim3(256), 0, stream>>>(WQb, WKb, WVb, Q, K, V);

  proj_kernel<<<dim3(6, 16, 4), dim3(256), 0, stream>>>(app, WQw, WKw, WVw,
                                                        Q, K, V);

  score_kernel<<<dim3(16, 16), dim3(256), 0, stream>>>(Q, K, S);

  bias_kernel<<<dim3(2048), dim3(256), 0, stream>>>(pos, S, WGw, WGb);

  softmax_pv_kernel<<<dim3(1024), dim3(256), 0, stream>>>(S, V, out);
}

// Round 3
// 787.504 us; speedup vs baseline: 1.0406x; 1.0342x over previous
//
#include <hip/hip_runtime.h>
#include <hip/hip_bf16.h>
#include <math.h>

#define N_PROP 1024
#define DAPP   2048
#define DK     128

// ---------------------------------------------------------------------------
// Kernel 0: seed Q/K/V with their biases (ws is poisoned 0xAA before each call)
// ---------------------------------------------------------------------------
__global__ __launch_bounds__(256) void init_bias_kernel(
    const float* __restrict__ bQ, const float* __restrict__ bK,
    const float* __restrict__ bV,
    float* __restrict__ Q, float* __restrict__ K, float* __restrict__ V) {
  int i = blockIdx.x * 256 + threadIdx.x;
  if (i < N_PROP * DK) {
    int c = i & (DK - 1);
    Q[i] = bQ[c];
    K[i] = bK[c];
    V[i] = bV[c];
  }
}

// ---------------------------------------------------------------------------
// Kernel 1: fused QKV projection.  C = X (1024x2048) @ W^T (2048x128) per proj.
// 64x64 output tile, 4x4 register blocking, split-k=4 via atomicAdd.
// grid = (6 col-tiles [3 proj x 2], 16 row-tiles, 4 k-splits), block = 256.
// ---------------------------------------------------------------------------
#define BM 64
#define BN 64
#define KC 32
#define KSPLIT_CHUNK 512

__global__ __launch_bounds__(256) void proj_kernel(
    const float* __restrict__ X,
    const float* __restrict__ WQ, const float* __restrict__ WK,
    const float* __restrict__ WV,
    float* __restrict__ Q, float* __restrict__ K, float* __restrict__ V) {
  __shared__ __attribute__((aligned(16))) float As[KC][BM + 4];
  __shared__ __attribute__((aligned(16))) float Bs[KC][BN + 4];

  const int nt = blockIdx.x;        // 0..5 : which 64-col slab of the 384 cols
  const int mt = blockIdx.y;        // 0..15
  const int kz = blockIdx.z;        // 0..3
  const int row0 = mt * BM;
  const int proj = nt >> 1;         // 0=Q 1=K 2=V
  const int col0 = (nt & 1) * 64;   // col offset inside the 128-wide proj

  const float* __restrict__ W = (proj == 0) ? WQ : ((proj == 1) ? WK : WV);
  float* __restrict__ O = (proj == 0) ? Q : ((proj == 1) ? K : V);

  const int t  = threadIdx.x;
  const int tx = t & 15, ty = t >> 4;   // 16x16 thread grid, 4x4 each
  const int kk = t & 31, mm = t >> 5;   // loader coords

  float acc[4][4] = {};

  const int k0base = kz * KSPLIT_CHUNK;
  for (int k0 = k0base; k0 < k0base + KSPLIT_CHUNK; k0 += KC) {
    __syncthreads();
#pragma unroll
    for (int r = 0; r < 8; ++r) {
      As[kk][mm + r * 8] = X[(size_t)(row0 + mm + r * 8) * DAPP + k0 + kk];
      Bs[kk][mm + r * 8] = W[(size_t)(col0 + mm + r * 8) * DAPP + k0 + kk];
    }
    __syncthreads();
#pragma unroll
    for (int k = 0; k < KC; ++k) {
      float4 a = *(const float4*)&As[k][ty * 4];
      float4 b = *(const float4*)&Bs[k][tx * 4];
      acc[0][0] += a.x * b.x; acc[0][1] += a.x * b.y; acc[0][2] += a.x * b.z; acc[0][3] += a.x * b.w;
      acc[1][0] += a.y * b.x; acc[1][1] += a.y * b.y; acc[1][2] += a.y * b.z; acc[1][3] += a.y * b.w;
      acc[2][0] += a.z * b.x; acc[2][1] += a.z * b.y; acc[2][2] += a.z * b.z; acc[2][3] += a.z * b.w;
      acc[3][0] += a.w * b.x; acc[3][1] += a.w * b.y; acc[3][2] += a.w * b.z; acc[3][3] += a.w * b.w;
    }
  }

#pragma unroll
  for (int i = 0; i < 4; ++i)
#pragma unroll
    for (int j = 0; j < 4; ++j)
      atomicAdd(&O[(size_t)(row0 + ty * 4 + i) * DK + col0 + tx * 4 + j],
                acc[i][j]);
}

// ---------------------------------------------------------------------------
// Kernel 2: S = (Q @ K^T) / sqrt(128).  1024x1024 output, k=128.
// grid = (16, 16), block = 256.
// ---------------------------------------------------------------------------
__global__ __launch_bounds__(256) void score_kernel(
    const float* __restrict__ Q, const float* __restrict__ Kmat,
    float* __restrict__ S) {
  __shared__ __attribute__((aligned(16))) float As[KC][BM + 4];
  __shared__ __attribute__((aligned(16))) float Bs[KC][BN + 4];

  const int col0 = blockIdx.x * BN;
  const int row0 = blockIdx.y * BM;
  const int t  = threadIdx.x;
  const int tx = t & 15, ty = t >> 4;
  const int kk = t & 31, mm = t >> 5;

  float acc[4][4] = {};

  for (int k0 = 0; k0 < DK; k0 += KC) {
    __syncthreads();
#pragma unroll
    for (int r = 0; r < 8; ++r) {
      As[kk][mm + r * 8] = Q[(size_t)(row0 + mm + r * 8) * DK + k0 + kk];
      Bs[kk][mm + r * 8] = Kmat[(size_t)(col0 + mm + r * 8) * DK + k0 + kk];
    }
    __syncthreads();
#pragma unroll
    for (int k = 0; k < KC; ++k) {
      float4 a = *(const float4*)&As[k][ty * 4];
      float4 b = *(const float4*)&Bs[k][tx * 4];
      acc[0][0] += a.x * b.x; acc[0][1] += a.x * b.y; acc[0][2] += a.x * b.z; acc[0][3] += a.x * b.w;
      acc[1][0] += a.y * b.x; acc[1][1] += a.y * b.y; acc[1][2] += a.y * b.z; acc[1][3] += a.y * b.w;
      acc[2][0] += a.z * b.x; acc[2][1] += a.z * b.y; acc[2][2] += a.z * b.z; acc[2][3] += a.z * b.w;
      acc[3][0] += a.w * b.x; acc[3][1] += a.w * b.y; acc[3][2] += a.w * b.z; acc[3][3] += a.w * b.w;
    }
  }

  const float scale = 0.08838834764831845f; // 1/sqrt(128)
#pragma unroll
  for (int i = 0; i < 4; ++i)
#pragma unroll
    for (int j = 0; j < 4; ++j)
      S[(size_t)(row0 + ty * 4 + i) * N_PROP + col0 + tx * 4 + j] =
          acc[i][j] * scale;
}

// ---------------------------------------------------------------------------
// Kernel 3: geometric bias, pure stream of the 512 MiB pos tensor.
// G[row] = relu(pos[row,:].wg + bg), row in [0, 1M).
// Unroll x4: each 32-lane half-wave handles 4 consecutive rows per iteration
// (4 independent coalesced 512B loads in flight), 4 interleaved shuffle
// reduces, one float4 store by lane 0.  No read-modify-write.
// grid = 2048 blocks x 256 thr = 8 blocks/CU; 16 grid-stride iterations.
// ---------------------------------------------------------------------------
__global__ __launch_bounds__(256) void bias_kernel(
    const float* __restrict__ pos, float* __restrict__ G,
    const float* __restrict__ wg, const float* __restrict__ bg) {
  const int t  = threadIdx.x;
  const int l  = t & 31;     // lane in half-wave
  const int hw = t >> 5;     // half-wave id 0..7

  const float4 w4 = *(const float4*)&wg[l * 4];   // 32 lanes cover 128 dims
  const float bG = bg[0];

  const size_t total  = (size_t)N_PROP * N_PROP;      // 1,048,576 rows
  const size_t stride = (size_t)gridDim.x * 32;       // 32 rows per block-iter
  for (size_t r0 = (size_t)blockIdx.x * 32 + hw * 4; r0 < total; r0 += stride) {
    const float* __restrict__ pr = pos + r0 * DK + (l << 2);
    const float4 p0 = *(const float4*)(pr);
    const float4 p1 = *(const float4*)(pr + DK);
    const float4 p2 = *(const float4*)(pr + 2 * DK);
    const float4 p3 = *(const float4*)(pr + 3 * DK);

    float d0 = fmaf(p0.x, w4.x, fmaf(p0.y, w4.y, fmaf(p0.z, w4.z, p0.w * w4.w)));
    float d1 = fmaf(p1.x, w4.x, fmaf(p1.y, w4.y, fmaf(p1.z, w4.z, p1.w * w4.w)));
    float d2 = fmaf(p2.x, w4.x, fmaf(p2.y, w4.y, fmaf(p2.z, w4.z, p2.w * w4.w)));
    float d3 = fmaf(p3.x, w4.x, fmaf(p3.y, w4.y, fmaf(p3.z, w4.z, p3.w * w4.w)));

#pragma unroll
    for (int off = 16; off; off >>= 1) {   // stays within the 32-lane half
      d0 += __shfl_xor(d0, off, 64);
      d1 += __shfl_xor(d1, off, 64);
      d2 += __shfl_xor(d2, off, 64);
      d3 += __shfl_xor(d3, off, 64);
    }
    if (l == 0) {
      float4 g;
      g.x = fmaxf(d0 + bG, 0.0f);
      g.y = fmaxf(d1 + bG, 0.0f);
      g.z = fmaxf(d2 + bG, 0.0f);
      g.w = fmaxf(d3 + bG, 0.0f);
      *(float4*)&G[r0] = g;
    }
  }
}

// ---------------------------------------------------------------------------
// Kernel 4: per-row softmax(S+G) + P@V.  One block per row m.
// S,G rows read as float4; PV unrolled x4 (V is L2-resident, 512 KB).
// ---------------------------------------------------------------------------
__global__ __launch_bounds__(256) void softmax_pv_kernel(
    const float* __restrict__ S, const float* __restrict__ G,
    const float* __restrict__ V, float* __restrict__ out) {
  __shared__ __attribute__((aligned(16))) float p[N_PROP];
  __shared__ __attribute__((aligned(16))) float4 accs[256];
  __shared__ float wred[4];

  const int m = blockIdx.x;
  const int t = threadIdx.x;
  const float* __restrict__ Srow = S + (size_t)m * N_PROP;
  const float* __restrict__ Grow = G + (size_t)m * N_PROP;

  // ---- logits = S + G ----
  const float4 sr = ((const float4*)Srow)[t];
  const float4 gr = ((const float4*)Grow)[t];
  const float4 s4 = make_float4(sr.x + gr.x, sr.y + gr.y, sr.z + gr.z, sr.w + gr.w);

  // ---- softmax ----
  float mx = fmaxf(fmaxf(s4.x, s4.y), fmaxf(s4.z, s4.w));
#pragma unroll
  for (int off = 32; off; off >>= 1) mx = fmaxf(mx, __shfl_xor(mx, off, 64));
  if ((t & 63) == 0) wred[t >> 6] = mx;
  __syncthreads();
  mx = fmaxf(fmaxf(wred[0], wred[1]), fmaxf(wred[2], wred[3]));

  const float e0 = __expf(s4.x - mx), e1 = __expf(s4.y - mx);
  const float e2 = __expf(s4.z - mx), e3 = __expf(s4.w - mx);
  ((float4*)p)[t] = make_float4(e0, e1, e2, e3);
  float sum = e0 + e1 + e2 + e3;
#pragma unroll
  for (int off = 32; off; off >>= 1) sum += __shfl_xor(sum, off, 64);
  __syncthreads();               // wred read-before-write hazard barrier
  if ((t & 63) == 0) wred[t >> 6] = sum;
  __syncthreads();               // also publishes p[]
  sum = wred[0] + wred[1] + wred[2] + wred[3];
  const float inv = 1.0f / sum;

  // ---- P @ V : 8 n-groups x 32 lanes x float4 cols, unroll x4 ----
  const int dq = (t & 31) << 2;  // col offset 0..124 (x4)
  const int ng = t >> 5;         // 0..7
  float4 acc = make_float4(0.f, 0.f, 0.f, 0.f);
  for (int n = ng; n < N_PROP; n += 32) {
    const float pw0 = p[n];
    const float pw1 = p[n + 8];
    const float pw2 = p[n + 16];
    const float pw3 = p[n + 24];
    const float4 v0 = *(const float4*)&V[(size_t)n * DK + dq];
    const float4 v1 = *(const float4*)&V[(size_t)(n + 8) * DK + dq];
    const float4 v2 = *(const float4*)&V[(size_t)(n + 16) * DK + dq];
    const float4 v3 = *(const float4*)&V[(size_t)(n + 24) * DK + dq];
    acc.x += pw0 * v0.x + pw1 * v1.x + pw2 * v2.x + pw3 * v3.x;
    acc.y += pw0 * v0.y + pw1 * v1.y + pw2 * v2.y + pw3 * v3.y;
    acc.z += pw0 * v0.z + pw1 * v1.z + pw2 * v2.z + pw3 * v3.z;
    acc.w += pw0 * v0.w + pw1 * v1.w + pw2 * v2.w + pw3 * v3.w;
  }
  accs[t] = acc;
  __syncthreads();
  if (t < 32) {
    float4 r = accs[t];
#pragma unroll
    for (int g = 1; g < 8; ++g) {
      const float4 o = accs[t + g * 32];
      r.x += o.x; r.y += o.y; r.z += o.z; r.w += o.w;
    }
    r.x *= inv; r.y *= inv; r.z *= inv; r.w *= inv;
    *(float4*)&out[(size_t)m * DK + (t << 2)] = r;
  }
}

// ---------------------------------------------------------------------------
extern "C" void kernel_launch(void* const* d_in, const int* in_sizes, int n_in,
                              void* d_out, int out_size, void* d_ws,
                              size_t ws_size, hipStream_t stream) {
  const float* app = (const float*)d_in[0];   // (1024, 2048)
  const float* pos = (const float*)d_in[1];   // (1024, 1024, 128)
  const float* WQw = (const float*)d_in[2];
  const float* WQb = (const float*)d_in[3];
  const float* WKw = (const float*)d_in[4];
  const float* WKb = (const float*)d_in[5];
  const float* WVw = (const float*)d_in[6];
  const float* WVb = (const float*)d_in[7];
  const float* WGw = (const float*)d_in[8];
  const float* WGb = (const float*)d_in[9];
  float* out = (float*)d_out;

  float* ws = (float*)d_ws;
  float* Q = ws;                         // 1024*128
  float* K = ws + 131072;                // 1024*128
  float* V = ws + 262144;                // 1024*128
  float* S = ws + 393216;                // 1024*1024
  float* G = ws + 393216 + 1048576;      // 1024*1024

  init_bias_kernel<<<dim3(512), dim3(256), 0, stream>>>(WQb, WKb, WVb, Q, K, V);

  proj_kernel<<<dim3(6, 16, 4), dim3(256), 0, stream>>>(app, WQw, WKw, WVw,
                                                        Q, K, V);

  score_kernel<<<dim3(16, 16), dim3(256), 0, stream>>>(Q, K, S);

  bias_kernel<<<dim3(2048), dim3(256), 0, stream>>>(pos, G, WGw, WGb);

  softmax_pv_kernel<<<dim3(1024), dim3(256), 0, stream>>>(S, G, V, out);
}